// Round 1
// baseline (662.329 us; speedup 1.0000x reference)
//
#include <hip/hip_runtime.h>
#include <cmath>

// LabelSmoothing KL-div sum, algebraically reduced:
//   per non-padding row: base*(V-2)*log(base) - base*(S - x0 - xt) + conf*(log(conf) - xt)
// where S = row sum of model_output. Pure streaming reduction, memory-bound.

#define V 32000
#define NROWS 4096

__global__ __launch_bounds__(256) void ls_rowsum_kernel(
    const float* __restrict__ x,
    const int* __restrict__ tgt,
    float* __restrict__ partial,
    float k_const,   // base*(V-2)*log(base)
    float base,      // smoothing/(V-1)
    float conf,      // 0.9
    float log_conf)  // log(0.9)
{
    const int row = blockIdx.x;
    const int t = tgt[row];
    if (t == 0) {
        if (threadIdx.x == 0) partial[row] = 0.0f;
        return;  // padding row: contributes nothing
    }

    const float* xrow = x + (size_t)row * V;
    const float4* xr4 = reinterpret_cast<const float4*>(xrow);

    // V/4 = 8000 float4 per row, 256 threads -> ~31.25 iters/thread
    float s = 0.0f;
    for (int i = threadIdx.x; i < V / 4; i += 256) {
        float4 v = xr4[i];
        s += (v.x + v.y) + (v.z + v.w);
    }

    // wave64 butterfly reduce
    #pragma unroll
    for (int off = 32; off > 0; off >>= 1)
        s += __shfl_down(s, off, 64);

    __shared__ float wsum[4];
    const int lane = threadIdx.x & 63;
    const int wave = threadIdx.x >> 6;
    if (lane == 0) wsum[wave] = s;
    __syncthreads();

    if (threadIdx.x == 0) {
        float S = (wsum[0] + wsum[1]) + (wsum[2] + wsum[3]);
        float x0 = xrow[0];
        float xt = xrow[t];
        partial[row] = k_const - base * (S - x0 - xt) + conf * (log_conf - xt);
    }
}

__global__ __launch_bounds__(1024) void ls_reduce_kernel(
    const float* __restrict__ partial,
    float* __restrict__ out)
{
    // 4096 partials -> 1 scalar; accumulate in double for stability.
    double s = 0.0;
    for (int i = threadIdx.x; i < NROWS; i += 1024)
        s += (double)partial[i];

    #pragma unroll
    for (int off = 32; off > 0; off >>= 1)
        s += __shfl_down(s, off, 64);

    __shared__ double wsum[16];
    const int lane = threadIdx.x & 63;
    const int wave = threadIdx.x >> 6;
    if (lane == 0) wsum[wave] = s;
    __syncthreads();

    if (threadIdx.x == 0) {
        double tot = 0.0;
        #pragma unroll
        for (int w = 0; w < 16; ++w) tot += wsum[w];
        out[0] = (float)tot;
    }
}

extern "C" void kernel_launch(void* const* d_in, const int* in_sizes, int n_in,
                              void* d_out, int out_size, void* d_ws, size_t ws_size,
                              hipStream_t stream) {
    const float* x = (const float*)d_in[0];
    const int* tgt = (const int*)d_in[1];
    float* out = (float*)d_out;
    float* partial = (float*)d_ws;  // 4096 floats = 16 KB

    const double base_d = 0.1 / (double)(V - 1);
    const float k_const = (float)(base_d * (double)(V - 2) * std::log(base_d));
    const float base_f = (float)base_d;
    const float conf_f = 0.9f;
    const float log_conf = (float)std::log(0.9);

    hipLaunchKernelGGL(ls_rowsum_kernel, dim3(NROWS), dim3(256), 0, stream,
                       x, tgt, partial, k_const, base_f, conf_f, log_conf);
    hipLaunchKernelGGL(ls_reduce_kernel, dim3(1), dim3(1024), 0, stream,
                       partial, out);
}

// Round 2
// 659.222 us; speedup vs baseline: 1.0047x; 1.0047x over previous
//
#include <hip/hip_runtime.h>
#include <cmath>

// LabelSmoothing KL-div sum, algebraically reduced:
//   per non-padding row (t != 0):
//     K - base*(S - x0 - xt) + conf*(log(conf) - xt),  K = base*(V-2)*log(base)
// where S = row-sum of model_output. Pure streaming read, memory-bound.
// Roofline: 4096*32000*4 B = 524 MB / 6.3 TB/s ~= 83 us.

#define V 32000
#define NROWS 4096
#define TPB 256

__global__ __launch_bounds__(TPB) void ls_rowsum_kernel(
    const float* __restrict__ x,
    const int* __restrict__ tgt,
    float* __restrict__ partial,
    float k_const,   // base*(V-2)*log(base)
    float base,      // smoothing/(V-1)
    float conf,      // 0.9
    float log_conf)  // log(0.9)
{
    const int row = blockIdx.x;
    const int t = tgt[row];

    const float* xrow = x + (size_t)row * V;
    const float4* xr4 = reinterpret_cast<const float4*>(xrow);

    // V/4 = 8000 float4 per row. Unroll-by-4 with independent accumulators:
    // 4 outstanding 16B loads per lane -> latency-hiding via MLP, not just TLP.
    // 8000 = 1024*7 + 832, so do 7 full unrolled passes + tail.
    float s0 = 0.f, s1 = 0.f, s2 = 0.f, s3 = 0.f;
    int i = threadIdx.x;
    #pragma unroll 1
    for (int it = 0; it < 7; ++it, i += 4 * TPB) {
        float4 a = xr4[i];
        float4 b = xr4[i + TPB];
        float4 c = xr4[i + 2 * TPB];
        float4 d = xr4[i + 3 * TPB];
        s0 += (a.x + a.y) + (a.z + a.w);
        s1 += (b.x + b.y) + (b.z + b.w);
        s2 += (c.x + c.y) + (c.z + c.w);
        s3 += (d.x + d.y) + (d.z + d.w);
    }
    // tail: 8000 - 7*1024 = 832 float4, i in [7168 + tid, 8000)
    for (; i < V / 4; i += TPB) {
        float4 a = xr4[i];
        s0 += (a.x + a.y) + (a.z + a.w);
    }
    float s = (s0 + s1) + (s2 + s3);

    // wave64 butterfly reduce
    #pragma unroll
    for (int off = 32; off > 0; off >>= 1)
        s += __shfl_down(s, off, 64);

    __shared__ float wsum[TPB / 64];
    const int lane = threadIdx.x & 63;
    const int wave = threadIdx.x >> 6;
    if (lane == 0) wsum[wave] = s;
    __syncthreads();

    if (threadIdx.x == 0) {
        float S = 0.f;
        #pragma unroll
        for (int w = 0; w < TPB / 64; ++w) S += wsum[w];
        float x0 = xrow[0];
        float xt = xrow[t];
        // padding row (t==0) contributes exactly 0
        partial[row] = (t == 0) ? 0.0f
                     : k_const - base * (S - x0 - xt) + conf * (log_conf - xt);
    }
}

__global__ __launch_bounds__(1024) void ls_reduce_kernel(
    const float* __restrict__ partial,
    float* __restrict__ out)
{
    // 4096 partials -> 1 scalar; accumulate in double for stability.
    double s = 0.0;
    for (int i = threadIdx.x; i < NROWS; i += 1024)
        s += (double)partial[i];

    #pragma unroll
    for (int off = 32; off > 0; off >>= 1)
        s += __shfl_down(s, off, 64);

    __shared__ double wsum[16];
    const int lane = threadIdx.x & 63;
    const int wave = threadIdx.x >> 6;
    if (lane == 0) wsum[wave] = s;
    __syncthreads();

    if (threadIdx.x == 0) {
        double tot = 0.0;
        #pragma unroll
        for (int w = 0; w < 16; ++w) tot += wsum[w];
        out[0] = (float)tot;
    }
}

extern "C" void kernel_launch(void* const* d_in, const int* in_sizes, int n_in,
                              void* d_out, int out_size, void* d_ws, size_t ws_size,
                              hipStream_t stream) {
    const float* x = (const float*)d_in[0];
    const int* tgt = (const int*)d_in[1];
    float* out = (float*)d_out;
    float* partial = (float*)d_ws;  // 4096 floats = 16 KB

    const double base_d = 0.1 / (double)(V - 1);
    const float k_const = (float)(base_d * (double)(V - 2) * std::log(base_d));
    const float base_f = (float)base_d;
    const float conf_f = 0.9f;
    const float log_conf = (float)std::log(0.9);

    hipLaunchKernelGGL(ls_rowsum_kernel, dim3(NROWS), dim3(TPB), 0, stream,
                       x, tgt, partial, k_const, base_f, conf_f, log_conf);
    hipLaunchKernelGGL(ls_reduce_kernel, dim3(1), dim3(1024), 0, stream,
                       partial, out);
}